// Round 3
// baseline (1875.634 us; speedup 1.0000x reference)
//
#include <hip/hip_runtime.h>

// Problem constants
#define BATCH 32
#define CDIM 256
#define HW 4096            // 64*64
#define NVEC 131072        // BATCH*HW
#define NE 1024
#define DECAY 0.99f
#define ONE_MINUS_DECAY 0.01f
#define EPSV 1e-5f
#define ZQ_ELEMS 33554432  // BATCH*CDIM*HW

// ---------------- K0: transpose embedding [1024,256] -> embT [256,1024] ----------------
__global__ __launch_bounds__(256) void prep_kernel(
    const float* __restrict__ emb, float* __restrict__ embT) {
  __shared__ float tile[32][33];
  int k0 = blockIdx.x * 32;   // 8 k-tiles
  int e0 = blockIdx.y * 32;   // 32 e-tiles
  int tx = threadIdx.x;       // 0..31
  int ty = threadIdx.y;       // 0..7
  #pragma unroll
  for (int j = 0; j < 32; j += 8)
    tile[ty + j][tx] = emb[(size_t)(e0 + ty + j) * CDIM + k0 + tx];
  __syncthreads();
  #pragma unroll
  for (int j = 0; j < 32; j += 8)
    embT[(size_t)(k0 + ty + j) * NE + e0 + tx] = tile[tx][ty + j];
}

// ---------------- K1: embedding row squared norms ----------------
__global__ __launch_bounds__(256) void enorm_kernel(
    const float* __restrict__ emb, float* __restrict__ enorm) {
  int gid  = blockIdx.x * 256 + threadIdx.x;
  int e    = gid >> 6;          // wave index = embedding row
  int lane = threadIdx.x & 63;
  const float4* row = (const float4*)(emb + ((size_t)e << 8));
  float4 v = row[lane];
  float s = v.x * v.x + v.y * v.y + v.z * v.z + v.w * v.w;
  #pragma unroll
  for (int off = 32; off > 0; off >>= 1) s += __shfl_down(s, off);
  if (lane == 0) enorm[e] = s;
}

// ---------------- K2: argmin over codebook + counts + idx outputs ----------------
// thread = one z-vector. ET=128 accumulators MUST be in VGPRs:
// __launch_bounds__(256, 1) lifts the allocator's occupancy-driven VGPR cap
// (without it: VGPR_Count=72, acc[] spilled to scratch, 1490us @ 45% VALU).
// embT rows are wave-uniform contiguous -> s_load_dwordx16 on the scalar
// pipe; inner body is a single v_fmac_f32 with SGPR operand.
#define ET 128
__global__ __launch_bounds__(256, 1) void argmin_kernel(
    const float* __restrict__ z, const float* __restrict__ embT,
    const float* __restrict__ enorm, int* __restrict__ idx_ws,
    float* __restrict__ idx_out, float* __restrict__ counts) {
  int n  = blockIdx.x * 256 + threadIdx.x;
  int b  = n >> 12;
  int hw = n & 4095;
  const float* zp = z + ((size_t)b << 20) + hw;  // element k at zp[k*4096]

  float best = 3.0e38f;
  int bi = 0;

  #pragma unroll 1
  for (int et = 0; et < NE; et += ET) {
    float acc[ET];
    #pragma unroll
    for (int e = 0; e < ET; ++e) acc[e] = 0.0f;

    #pragma unroll 2
    for (int k = 0; k < CDIM; ++k) {
      float zk = zp[(size_t)k << 12];
      const float* row = embT + ((size_t)k << 10) + et;  // wave-uniform
      #pragma unroll
      for (int e = 0; e < ET; ++e)
        acc[e] = fmaf(zk, row[e], acc[e]);
    }

    #pragma unroll
    for (int e = 0; e < ET; ++e) {
      float d = enorm[et + e] - 2.0f * acc[e];
      bool c = d < best;                 // strict < : first-min tie-break
      bi   = c ? (et + e) : bi;
      best = c ? d : best;
    }
  }

  idx_ws[n] = bi;
  idx_out[n] = (float)bi;
  atomicAdd(&counts[bi], 1.0f);
}

// ---------------- K3: z_q gather (NCHW) + loss partial, float4 ----------------
__global__ __launch_bounds__(256) void zq_loss_kernel(
    const float* __restrict__ z, const float* __restrict__ emb,
    const int* __restrict__ idx_ws, float* __restrict__ zq_out,
    float* __restrict__ loss_acc) {
  int stride = gridDim.x * 256;
  float lsum = 0.0f;
  const float4* z4 = (const float4*)z;
  const int4* idx4 = (const int4*)idx_ws;
  float4* zq4 = (float4*)zq_out;
  for (int o4 = blockIdx.x * 256 + threadIdx.x; o4 < ZQ_ELEMS / 4; o4 += stride) {
    int o  = o4 << 2;
    int hw = o & 4095;
    int c  = (o >> 12) & 255;
    int b  = o >> 20;
    int4 id = idx4[((b << 12) | hw) >> 2];
    float4 zv = z4[o4];
    float4 q;
    q.x = emb[((size_t)id.x << 8) + c];
    q.y = emb[((size_t)id.y << 8) + c];
    q.z = emb[((size_t)id.z << 8) + c];
    q.w = emb[((size_t)id.w << 8) + c];
    zq4[o4] = q;
    float dx = q.x - zv.x, dy = q.y - zv.y, dz = q.z - zv.z, dw = q.w - zv.w;
    lsum += dx * dx + dy * dy + dz * dz + dw * dw;
  }
  __shared__ float red[256];
  red[threadIdx.x] = lsum;
  __syncthreads();
  for (int s = 128; s > 0; s >>= 1) {
    if (threadIdx.x < s) red[threadIdx.x] += red[threadIdx.x + s];
    __syncthreads();
  }
  if (threadIdx.x == 0) atomicAdd(loss_acc, red[0]);
}

// ---------------- K4: emb_sum scatter via per-channel LDS histogram ----------------
__global__ __launch_bounds__(256) void embsum_kernel(
    const float* __restrict__ z, const int* __restrict__ idx_ws,
    float* __restrict__ emb_sum) {
  __shared__ float hist[NE];
  int t = threadIdx.x;
  #pragma unroll
  for (int i = t; i < NE; i += 256) hist[i] = 0.0f;
  __syncthreads();

  int c     = blockIdx.x & 255;
  int chunk = blockIdx.x >> 8;   // 0..7
  int base  = chunk << 14;       // *16384 vectors per chunk

  const int4* idx4 = (const int4*)idx_ws;
  for (int i4 = t; i4 < 4096; i4 += 256) {
    int n0 = base + (i4 << 2);
    int b  = n0 >> 12;
    int hw = n0 & 4095;
    float4 v = *(const float4*)(z + ((((size_t)(b << 8) + c) << 12) + hw));
    int4 id = idx4[n0 >> 2];
    atomicAdd(&hist[id.x], v.x);
    atomicAdd(&hist[id.y], v.y);
    atomicAdd(&hist[id.z], v.z);
    atomicAdd(&hist[id.w], v.w);
  }
  __syncthreads();

  for (int e = t; e < NE; e += 256)
    atomicAdd(&emb_sum[(e << 8) + c], hist[e]);
}

// ---------------- K5: new_cluster_size + n reduction + loss finalize ----------------
__global__ __launch_bounds__(1024) void ema_cs_kernel(
    const float* __restrict__ cs, const float* __restrict__ counts,
    float* __restrict__ out_ncs, float* __restrict__ n_ws,
    const float* __restrict__ loss_acc, float* __restrict__ loss_out) {
  int e = threadIdx.x;
  float ncs = cs[e] * DECAY + ONE_MINUS_DECAY * counts[e];
  out_ncs[e] = ncs;
  __shared__ float red[1024];
  red[e] = ncs;
  __syncthreads();
  for (int s = 512; s > 0; s >>= 1) {
    if (e < s) red[e] += red[e + s];
    __syncthreads();
  }
  if (e == 0) {
    n_ws[0] = red[0];
    loss_out[0] = loss_acc[0] * 2.0f / (float)ZQ_ELEMS;  // (1+beta)*mse
  }
}

// ---------------- K6: new_embedding_avg + new_embedding ----------------
__global__ __launch_bounds__(256) void ema_emb_kernel(
    const float* __restrict__ eavg, const float* __restrict__ emb_sum,
    const float* __restrict__ ncs, const float* __restrict__ n_ws,
    float* __restrict__ out_eavg, float* __restrict__ out_emb) {
  int i = blockIdx.x * 256 + threadIdx.x;  // 262144 elems
  int e = i >> 8;
  float ea = eavg[i] * DECAY + ONE_MINUS_DECAY * emb_sum[i];
  out_eavg[i] = ea;
  float nv   = n_ws[0];
  float ncse = ncs[e];
  float sm   = (ncse + EPSV) / (nv + (float)NE * EPSV) * nv;
  out_emb[i] = ea / sm;
}

extern "C" void kernel_launch(void* const* d_in, const int* in_sizes, int n_in,
                              void* d_out, int out_size, void* d_ws, size_t ws_size,
                              hipStream_t stream) {
  const float* z    = (const float*)d_in[0];  // [32,256,64,64]
  const float* emb  = (const float*)d_in[1];  // [1024,256]
  const float* eavg = (const float*)d_in[2];  // [1024,256]
  const float* cs   = (const float*)d_in[3];  // [1024]

  float* out = (float*)d_out;
  float* out_zq   = out;                         // 33554432
  float* out_loss = out + 33554432;              // 1
  float* out_idx  = out + 33554433;              // 131072
  float* out_emb  = out + 33685505;              // 262144
  float* out_eavg = out + 33947649;              // 262144
  float* out_ncs  = out + 34209793;              // 1024

  float* ws       = (float*)d_ws;
  float* emb_sum  = ws;                          // 262144
  float* counts   = ws + 262144;                 // 1024
  float* loss_acc = ws + 263168;                 // 1
  float* n_ws     = ws + 263169;                 // 1
  int*   idx_ws   = (int*)(ws + 263170);         // 131072 ints
  float* enorm    = ws + 263170 + 131072;        // 1024

  // embT scratch lives at the head of out_zq: argmin reads it, then
  // zq_loss_kernel overwrites the whole region.
  float* embT = out_zq;                          // 262144 floats

  hipMemsetAsync(ws, 0, (size_t)263170 * sizeof(float), stream);

  dim3 tb(32, 8);
  dim3 tg(CDIM / 32, NE / 32);
  prep_kernel<<<tg, tb, 0, stream>>>(emb, embT);
  enorm_kernel<<<NE / 4, 256, 0, stream>>>(emb, enorm);
  argmin_kernel<<<NVEC / 256, 256, 0, stream>>>(z, embT, enorm, idx_ws, out_idx, counts);
  zq_loss_kernel<<<2048, 256, 0, stream>>>(z, emb, idx_ws, out_zq, loss_acc);
  embsum_kernel<<<2048, 256, 0, stream>>>(z, idx_ws, emb_sum);
  ema_cs_kernel<<<1, 1024, 0, stream>>>(cs, counts, out_ncs, n_ws, loss_acc, out_loss);
  ema_emb_kernel<<<262144 / 256, 256, 0, stream>>>(eavg, emb_sum, out_ncs, n_ws, out_eavg, out_emb);
}

// Round 4
// 1172.965 us; speedup vs baseline: 1.5991x; 1.5991x over previous
//
#include <hip/hip_runtime.h>

// Problem constants
#define BATCH 32
#define CDIM 256
#define HW 4096            // 64*64
#define NVEC 131072        // BATCH*HW
#define NE 1024
#define DECAY 0.99f
#define ONE_MINUS_DECAY 0.01f
#define EPSV 1e-5f
#define ZQ_ELEMS 33554432  // BATCH*CDIM*HW

__device__ __forceinline__ void fma4(float a, const float4& b, float4& c) {
  c.x = fmaf(a, b.x, c.x);
  c.y = fmaf(a, b.y, c.y);
  c.z = fmaf(a, b.z, c.z);
  c.w = fmaf(a, b.w, c.w);
}

__device__ __forceinline__ float getc(const float4& v, int c) {
  switch (c & 3) {
    case 0: return v.x;
    case 1: return v.y;
    case 2: return v.z;
    default: return v.w;
  }
}

// ---------------- K0: transpose embedding [1024,256] -> embT [256,1024] ----------------
__global__ __launch_bounds__(256) void prep_kernel(
    const float* __restrict__ emb, float* __restrict__ embT) {
  __shared__ float tile[32][33];
  int k0 = blockIdx.x * 32;
  int e0 = blockIdx.y * 32;
  int tx = threadIdx.x;       // 0..31
  int ty = threadIdx.y;       // 0..7
  #pragma unroll
  for (int j = 0; j < 32; j += 8)
    tile[ty + j][tx] = emb[(size_t)(e0 + ty + j) * CDIM + k0 + tx];
  __syncthreads();
  #pragma unroll
  for (int j = 0; j < 32; j += 8)
    embT[(size_t)(k0 + ty + j) * NE + e0 + tx] = tile[tx][ty + j];
}

// ---------------- K1: embedding row squared norms ----------------
__global__ __launch_bounds__(256) void enorm_kernel(
    const float* __restrict__ emb, float* __restrict__ enorm) {
  int gid  = blockIdx.x * 256 + threadIdx.x;
  int e    = gid >> 6;
  int lane = threadIdx.x & 63;
  const float4* row = (const float4*)(emb + ((size_t)e << 8));
  float4 v = row[lane];
  float s = v.x * v.x + v.y * v.y + v.z * v.z + v.w * v.w;
  #pragma unroll
  for (int off = 32; off > 0; off >>= 1) s += __shfl_down(s, off);
  if (lane == 0) enorm[e] = s;
}

// ---------------- K2: argmin as tiled GEMM + argmin epilogue ----------------
// Macro tile 64n x 256e per block (256 thr), thread tile 4n x 16e as
// float4 acc[4][4] (the m97-proven register-promotable shape; ET=64/128
// flat arrays failed SROA twice -> scratch @ VGPR=72).
// 4 et-passes cover 1024 e with running per-n argmin; LDS cross-te reduce.
#define BK 16
#define ZS_LD 68    // z LDS row stride (pad: 68%32=4 -> bank shift per row)
#define ES_LD 260   // emb LDS row stride (260%32=4)
__global__ __launch_bounds__(256, 3) void argmin_kernel(
    const float* __restrict__ z, const float* __restrict__ embT,
    const float* __restrict__ enorm, int* __restrict__ idx_ws,
    float* __restrict__ idx_out, float* __restrict__ counts) {
  __shared__ float zs[BK][ZS_LD];
  __shared__ float es[BK][ES_LD];
  __shared__ float rbest[16][64];
  __shared__ int   ridx[16][64];

  int t  = threadIdx.x;
  int tn = t & 15;            // n-group (4 n each)
  int te = t >> 4;            // e-group (16 e each)
  int n0 = blockIdx.x * 64;
  int b  = n0 >> 12;
  int hw0 = n0 & 4095;        // 64-aligned, stays within one b
  const float* zb = z + ((size_t)b << 20) + hw0;

  int lk = t >> 4;            // staging row (k within chunk)
  int ln = (t & 15) * 4;      // staging z col
  int le = (t & 15) * 16;     // staging emb col

  float bestd[4] = {3.0e38f, 3.0e38f, 3.0e38f, 3.0e38f};
  int   besti[4] = {0, 0, 0, 0};

  #pragma unroll 1
  for (int et = 0; et < 4; ++et) {
    float4 acc[4][4];
    #pragma unroll
    for (int i = 0; i < 4; ++i)
      #pragma unroll
      for (int j = 0; j < 4; ++j)
        acc[i][j] = make_float4(0.f, 0.f, 0.f, 0.f);

    #pragma unroll 1
    for (int kc = 0; kc < CDIM; kc += BK) {
      __syncthreads();  // previous chunk's reads complete
      // stage z-tile [BK][64]
      *(float4*)&zs[lk][ln] =
          *(const float4*)(zb + (size_t)(kc + lk) * HW + ln);
      // stage emb-tile [BK][256]
      const float* ep = embT + (size_t)(kc + lk) * NE + et * 256 + le;
      *(float4*)&es[lk][le]      = *(const float4*)(ep);
      *(float4*)&es[lk][le + 4]  = *(const float4*)(ep + 4);
      *(float4*)&es[lk][le + 8]  = *(const float4*)(ep + 8);
      *(float4*)&es[lk][le + 12] = *(const float4*)(ep + 12);
      __syncthreads();

      #pragma unroll 2
      for (int k = 0; k < BK; ++k) {
        const float4 zv = *(const float4*)&zs[k][tn * 4];
        const float4 e0 = *(const float4*)&es[k][te * 16];
        const float4 e1 = *(const float4*)&es[k][te * 16 + 4];
        const float4 e2 = *(const float4*)&es[k][te * 16 + 8];
        const float4 e3 = *(const float4*)&es[k][te * 16 + 12];
        #pragma unroll
        for (int i = 0; i < 4; ++i) {
          const float zi = getc(zv, i);
          fma4(zi, e0, acc[i][0]);
          fma4(zi, e1, acc[i][1]);
          fma4(zi, e2, acc[i][2]);
          fma4(zi, e3, acc[i][3]);
        }
      }
    }

    // epilogue for this et: distances + running argmin (e ascending)
    #pragma unroll
    for (int i = 0; i < 4; ++i) {
      #pragma unroll
      for (int jq = 0; jq < 4; ++jq) {
        #pragma unroll
        for (int jc = 0; jc < 4; ++jc) {
          int e = et * 256 + te * 16 + jq * 4 + jc;
          float d = enorm[e] - 2.0f * getc(acc[i][jq], jc);
          if (d < bestd[i]) { bestd[i] = d; besti[i] = e; }
        }
      }
    }
  }

  // cross-te reduce (te ascending keeps lowest-e on exact ties within pass)
  #pragma unroll
  for (int i = 0; i < 4; ++i) {
    rbest[te][tn * 4 + i] = bestd[i];
    ridx[te][tn * 4 + i]  = besti[i];
  }
  __syncthreads();
  if (t < 64) {
    float bd = rbest[0][t];
    int   bi = ridx[0][t];
    #pragma unroll
    for (int g = 1; g < 16; ++g) {
      float d = rbest[g][t];
      if (d < bd) { bd = d; bi = ridx[g][t]; }
    }
    int n = n0 + t;
    idx_ws[n] = bi;
    idx_out[n] = (float)bi;
    atomicAdd(&counts[bi], 1.0f);
  }
}

// ---------------- K3: fused z_q gather + loss + emb_sum histogram ----------------
// block = (channel c, n-chunk). Reads z once, writes zq, LDS float hist.
__global__ __launch_bounds__(256) void fused_scatter_kernel(
    const float* __restrict__ z, const float* __restrict__ emb,
    const int* __restrict__ idx_ws, float* __restrict__ zq_out,
    float* __restrict__ loss_acc, float* __restrict__ emb_sum) {
  __shared__ float hist[NE];
  int t = threadIdx.x;
  #pragma unroll
  for (int i = t; i < NE; i += 256) hist[i] = 0.0f;
  __syncthreads();

  int c     = blockIdx.x & 255;
  int chunk = blockIdx.x >> 8;   // 0..7
  int base  = chunk << 14;       // 16384 vectors per chunk

  float lsum = 0.0f;
  const int4* idx4 = (const int4*)idx_ws;
  for (int i4 = t; i4 < 4096; i4 += 256) {
    int n0 = base + (i4 << 2);
    int b  = n0 >> 12;
    int hw = n0 & 4095;
    size_t off = (((size_t)(b << 8) + c) << 12) + hw;
    float4 v = *(const float4*)(z + off);
    int4 id = idx4[n0 >> 2];
    float4 q;
    q.x = emb[((size_t)id.x << 8) + c];
    q.y = emb[((size_t)id.y << 8) + c];
    q.z = emb[((size_t)id.z << 8) + c];
    q.w = emb[((size_t)id.w << 8) + c];
    *(float4*)(zq_out + off) = q;
    float dx = q.x - v.x, dy = q.y - v.y, dz = q.z - v.z, dw = q.w - v.w;
    lsum += dx * dx + dy * dy + dz * dz + dw * dw;
    atomicAdd(&hist[id.x], v.x);
    atomicAdd(&hist[id.y], v.y);
    atomicAdd(&hist[id.z], v.z);
    atomicAdd(&hist[id.w], v.w);
  }
  __syncthreads();

  for (int e = t; e < NE; e += 256)
    atomicAdd(&emb_sum[(e << 8) + c], hist[e]);

  __shared__ float red[256];
  red[t] = lsum;
  __syncthreads();
  for (int s = 128; s > 0; s >>= 1) {
    if (t < s) red[t] += red[t + s];
    __syncthreads();
  }
  if (t == 0) atomicAdd(loss_acc, red[0]);
}

// ---------------- K5: new_cluster_size + n reduction + loss finalize ----------------
__global__ __launch_bounds__(1024) void ema_cs_kernel(
    const float* __restrict__ cs, const float* __restrict__ counts,
    float* __restrict__ out_ncs, float* __restrict__ n_ws,
    const float* __restrict__ loss_acc, float* __restrict__ loss_out) {
  int e = threadIdx.x;
  float ncs = cs[e] * DECAY + ONE_MINUS_DECAY * counts[e];
  out_ncs[e] = ncs;
  __shared__ float red[1024];
  red[e] = ncs;
  __syncthreads();
  for (int s = 512; s > 0; s >>= 1) {
    if (e < s) red[e] += red[e + s];
    __syncthreads();
  }
  if (e == 0) {
    n_ws[0] = red[0];
    loss_out[0] = loss_acc[0] * 2.0f / (float)ZQ_ELEMS;  // (1+beta)*mse
  }
}

// ---------------- K6: new_embedding_avg + new_embedding ----------------
__global__ __launch_bounds__(256) void ema_emb_kernel(
    const float* __restrict__ eavg, const float* __restrict__ emb_sum,
    const float* __restrict__ ncs, const float* __restrict__ n_ws,
    float* __restrict__ out_eavg, float* __restrict__ out_emb) {
  int i = blockIdx.x * 256 + threadIdx.x;  // 262144 elems
  int e = i >> 8;
  float ea = eavg[i] * DECAY + ONE_MINUS_DECAY * emb_sum[i];
  out_eavg[i] = ea;
  float nv   = n_ws[0];
  float ncse = ncs[e];
  float sm   = (ncse + EPSV) / (nv + (float)NE * EPSV) * nv;
  out_emb[i] = ea / sm;
}

extern "C" void kernel_launch(void* const* d_in, const int* in_sizes, int n_in,
                              void* d_out, int out_size, void* d_ws, size_t ws_size,
                              hipStream_t stream) {
  const float* z    = (const float*)d_in[0];  // [32,256,64,64]
  const float* emb  = (const float*)d_in[1];  // [1024,256]
  const float* eavg = (const float*)d_in[2];  // [1024,256]
  const float* cs   = (const float*)d_in[3];  // [1024]

  float* out = (float*)d_out;
  float* out_zq   = out;                         // 33554432
  float* out_loss = out + 33554432;              // 1
  float* out_idx  = out + 33554433;              // 131072
  float* out_emb  = out + 33685505;              // 262144
  float* out_eavg = out + 33947649;              // 262144
  float* out_ncs  = out + 34209793;              // 1024

  // workspace layout (floats) — idx_ws FIRST so int4 loads are 16B-aligned
  float* ws       = (float*)d_ws;
  int*   idx_ws   = (int*)ws;                    // 131072 ints
  float* emb_sum  = ws + 131072;                 // 262144
  float* counts   = ws + 393216;                 // 1024
  float* loss_acc = ws + 394240;                 // 1
  float* n_ws     = ws + 394241;                 // 1
  float* enorm    = ws + 394244;                 // 1024

  // embT scratch at head of out_zq: argmin reads it, fused kernel overwrites.
  float* embT = out_zq;                          // 262144 floats

  // zero emb_sum + counts + loss + n
  hipMemsetAsync(ws + 131072, 0, (size_t)263170 * sizeof(float), stream);

  dim3 tb(32, 8);
  dim3 tg(CDIM / 32, NE / 32);
  prep_kernel<<<tg, tb, 0, stream>>>(emb, embT);
  enorm_kernel<<<NE / 4, 256, 0, stream>>>(emb, enorm);
  argmin_kernel<<<NVEC / 64, 256, 0, stream>>>(z, embT, enorm, idx_ws, out_idx, counts);
  fused_scatter_kernel<<<2048, 256, 0, stream>>>(z, emb, idx_ws, out_zq, loss_acc, emb_sum);
  ema_cs_kernel<<<1, 1024, 0, stream>>>(cs, counts, out_ncs, n_ws, loss_acc, out_loss);
  ema_emb_kernel<<<262144 / 256, 256, 0, stream>>>(eavg, emb_sum, out_ncs, n_ws, out_eavg, out_emb);
}